// Round 4
// baseline (1733.619 us; speedup 1.0000x reference)
//
#include <hip/hip_runtime.h>

// Problem constants (reference: M, B, D = 32, 64, 8192)
#define Mh 32
#define Bh 64
#define Dh 8192
#define STG  128          // k per LDS stage
#define NSTG 4            // stages per gram block (kch = 512)
#define NCHG 16           // k-chunks (gram grid = 64 b x 16)

typedef unsigned int  uint_t;
typedef unsigned short ush;

// async global->LDS DMA, 16 B per active lane; LDS dest = uniform base + lane*16
__device__ __forceinline__ void async_cp16(const float* g, float* l) {
    __builtin_amdgcn_global_load_lds((const __attribute__((address_space(1))) uint_t*)g,
                                     (__attribute__((address_space(3))) uint_t*)l, 16, 0, 0);
}

__device__ __forceinline__ uint_t bf16rne(float x) {
    uint_t u = __float_as_uint(x);
    return (u + 0x7FFFu + ((u >> 16) & 1u)) >> 16;
}

// ---------------------------------------------------------------------------
// Kernel A: batched Gram partials + bf16 repack of s,y into [b][kst][k'][i].
// grid = 64 b x 16 k-chunks, 256 threads, 33 KB LDS -> 4 blocks/CU.
// __launch_bounds__(256,4) caps VGPR at 128 (NO SPILLS is the design goal).
// ---------------------------------------------------------------------------
__global__ __launch_bounds__(256, 4) void gram_kernel(
    const float* __restrict__ s, const float* __restrict__ y,
    const float* __restrict__ frc, float* __restrict__ ws,
    ush* __restrict__ sB, ush* __restrict__ yB, int do_bf16,
    long off_psy, long off_pyy, long off_pvs, long off_pvy)
{
    __shared__ float sT[32 * STG];   // 16 KB
    __shared__ float yT[32 * STG];   // 16 KB
    __shared__ float fT[STG];        // 512 B

    const int b   = blockIdx.x & 63;
    const int ch  = blockIdx.x >> 6;          // 0..15 (partials index)
    const int chk = (ch + b) & 15;            // per-b chunk rotation (k decorrelation)
    const int rot = ch & 3;                   // per-block stage rotation
    const int t   = threadIdx.x;
    const int w   = t >> 6;
    const int l   = t & 63;
    const int tx  = l & 7;
    const int ty  = l >> 3;

    // staging geometry: wave w issues instrs j=4w..4w+3; instr j covers rows
    // 2j (lanes 0-31) and 2j+1 (lanes 32-63); global col = (l&31) ^ swz,
    // swz = (j>>1)&7 == (row>>2)&7 for both rows of the instr.
    size_t rowoff[4];
    int    ldsoff[4];
    #pragma unroll
    for (int jj = 0; jj < 4; ++jj) {
        const int j   = (w << 2) + jj;
        const int row = (j << 1) + (l >> 5);
        const int cg  = (l & 31) ^ ((j >> 1) & 7);
        rowoff[jj] = ((size_t)row * Bh + b) * Dh + (cg << 2);
        ldsoff[jj] = j << 8;                  // j * 256 floats (2 rows * STG)
    }
    const size_t fbase = (size_t)b * Dh;

    float acc_sy[4][4] = {};
    float acc_yy[4][4] = {};
    float avs[4] = {}, avy[4] = {};

    const int kb0 = chk * (NSTG * STG);

    // prologue DMA: stage (rot)
    {
        const int kg = kb0 + rot * STG;
        #pragma unroll
        for (int jj = 0; jj < 4; ++jj) {
            async_cp16(s + rowoff[jj] + kg, &sT[ldsoff[jj]]);
            async_cp16(y + rowoff[jj] + kg, &yT[ldsoff[jj]]);
        }
        if (t < 32) async_cp16(frc + fbase + kg + (l << 2), &fT[0]);
    }

    for (int st = 0; st < NSTG; ++st) {
        const int stc = (st + rot) & 3;       // current stage (rotated order)
        __syncthreads();                      // DMA for stc complete

        // ---- compute: wave w covers f4-cols 8w..8w+7 of this stage ----
        #pragma unroll
        for (int kk = 0; kk < 8; ++kk) {
            const int c0 = (w << 3) + kk;
            float4 xv[4];
            #pragma unroll
            for (int aa = 0; aa < 4; ++aa)
                xv[aa] = *(const float4*)&yT[((tx << 2) + aa) * STG + ((c0 ^ tx) << 2)];
            const float4 fv = *(const float4*)&fT[c0 << 2];
            #pragma unroll
            for (int aa = 0; aa < 4; ++aa) {
                const float4 sv = *(const float4*)&sT[((ty << 2) + aa) * STG + ((c0 ^ ty) << 2)];
                const float4 tv = *(const float4*)&yT[((ty << 2) + aa) * STG + ((c0 ^ ty) << 2)];
                #pragma unroll
                for (int cc = 0; cc < 4; ++cc) {
                    acc_sy[aa][cc] += sv.x * xv[cc].x + sv.y * xv[cc].y
                                    + sv.z * xv[cc].z + sv.w * xv[cc].w;
                    acc_yy[aa][cc] += tv.x * xv[cc].x + tv.y * xv[cc].y
                                    + tv.z * xv[cc].z + tv.w * xv[cc].w;
                }
                avs[aa] += sv.x * fv.x + sv.y * fv.y + sv.z * fv.z + sv.w * fv.w;
                avy[aa] += tv.x * fv.x + tv.y * fv.y + tv.z * fv.z + tv.w * fv.w;
            }
        }

        // ---- bf16 repack of this stage's tile: out layout [b][kst][k'][i] ----
        if (do_bf16) {
            const int kp  = t >> 1;           // k' 0..127
            const int ih  = (t & 1) << 4;     // i-half 0 / 16
            const int kg4 = kp >> 2, kl = kp & 3;
            const int kstG = chk * NSTG + stc;
            uint_t us[8], uy[8];
            #pragma unroll
            for (int r = 0; r < 16; r += 2) {
                const int i0 = ih + r, i1 = ih + r + 1;
                const int a0 = i0 * STG + (((kg4 ^ ((i0 >> 2) & 7)) << 2) | kl);
                const int a1 = i1 * STG + (((kg4 ^ ((i1 >> 2) & 7)) << 2) | kl);
                us[r >> 1] = bf16rne(sT[a0]) | (bf16rne(sT[a1]) << 16);
                uy[r >> 1] = bf16rne(yT[a0]) | (bf16rne(yT[a1]) << 16);
            }
            const size_t obase = (((size_t)b * 64 + kstG) * 128 + kp) * 32 + ih;
            *(uint4*)(sB + obase)     = make_uint4(us[0], us[1], us[2], us[3]);
            *(uint4*)(sB + obase + 8) = make_uint4(us[4], us[5], us[6], us[7]);
            *(uint4*)(yB + obase)     = make_uint4(uy[0], uy[1], uy[2], uy[3]);
            *(uint4*)(yB + obase + 8) = make_uint4(uy[4], uy[5], uy[6], uy[7]);
        }

        __syncthreads();                      // all LDS reads done
        if (st + 1 < NSTG) {
            const int kg = kb0 + ((st + 1 + rot) & 3) * STG;
            #pragma unroll
            for (int jj = 0; jj < 4; ++jj) {
                async_cp16(s + rowoff[jj] + kg, &sT[ldsoff[jj]]);
                async_cp16(y + rowoff[jj] + kg, &yT[ldsoff[jj]]);
            }
            if (t < 32) async_cp16(frc + fbase + kg + (l << 2), &fT[0]);
        }
    }

    // ---- cross-wave reduction (reuse sT: SY=sT[0:1024], YY=sT[1024:2048], VV=fT) ----
    __syncthreads();
    float* SY = &sT[0];
    float* YY = &sT[1024];
    float* VV = &fT[0];
    for (int wv = 0; wv < 4; ++wv) {
        if (w == wv) {
            #pragma unroll
            for (int aa = 0; aa < 4; ++aa) {
                #pragma unroll
                for (int cc = 0; cc < 4; ++cc) {
                    const int e = ((ty << 2) + aa) * 32 + (tx << 2) + cc;
                    if (wv == 0) { SY[e] = acc_sy[aa][cc];  YY[e] = acc_yy[aa][cc]; }
                    else         { SY[e] += acc_sy[aa][cc]; YY[e] += acc_yy[aa][cc]; }
                }
                if (tx == 0) {
                    const int i = (ty << 2) + aa;
                    if (wv == 0) { VV[i] = avs[aa];  VV[32 + i] = avy[aa]; }
                    else         { VV[i] += avs[aa]; VV[32 + i] += avy[aa]; }
                }
            }
        }
        __syncthreads();
    }

    float* PSY = ws + off_psy + ((size_t)ch * Bh + b) * 1024;
    float* PYY = ws + off_pyy + ((size_t)ch * Bh + b) * 1024;
    *(float4*)&PSY[t << 2] = *(const float4*)&SY[t << 2];
    *(float4*)&PYY[t << 2] = *(const float4*)&YY[t << 2];
    if (t < 32)      ws[off_pvs + (ch * 64 + b) * 32 + t] = VV[t];
    else if (t < 64) ws[off_pvy + (ch * 64 + b) * 32 + (t - 32)] = VV[t];
}

// ---------------------------------------------------------------------------
// Kernel B: reduce nch partials, then the M=32 f64 recursion. 1 block per b.
// ---------------------------------------------------------------------------
__global__ __launch_bounds__(256) void recur_kernel(
    float* __restrict__ ws, int nch,
    long off_psy, long off_pyy, long off_pvs, long off_pvy,
    long off_cy, long off_cs, long off_g)
{
    __shared__ float WSY[1024], WYY[1024], VS[32], VY[32];
    const int b = blockIdx.x;
    const int t = threadIdx.x;

    float4 a4 = make_float4(0.f, 0.f, 0.f, 0.f);
    float4 c4 = make_float4(0.f, 0.f, 0.f, 0.f);
    for (int ch = 0; ch < nch; ++ch) {
        const float4 u = *(const float4*)&ws[off_psy + ((size_t)ch * Bh + b) * 1024 + (t << 2)];
        const float4 v = *(const float4*)&ws[off_pyy + ((size_t)ch * Bh + b) * 1024 + (t << 2)];
        a4.x += u.x; a4.y += u.y; a4.z += u.z; a4.w += u.w;
        c4.x += v.x; c4.y += v.y; c4.z += v.z; c4.w += v.w;
    }
    *(float4*)&WSY[t << 2] = a4;
    *(float4*)&WYY[t << 2] = c4;
    if (t < 32) {
        float av = 0.f, cv = 0.f;
        for (int ch = 0; ch < nch; ++ch) {
            av += ws[off_pvs + (ch * 64 + b) * 32 + t];
            cv += ws[off_pvy + (ch * 64 + b) * 32 + t];
        }
        VS[t] = av; VY[t] = cv;
    }
    __syncthreads();
    if (t >= 64) return;

    const int i = t & 31;
    float row_sy[32], col_sy[32], row_yy[32];
    #pragma unroll
    for (int j = 0; j < 32; ++j) {
        row_sy[j] = WSY[i * 32 + j];
        col_sy[j] = WSY[j * 32 + i];
        row_yy[j] = WYY[i * 32 + j];
    }

    const double r = 1.0 / (double)row_sy[i];
    double acc = -(double)VS[i];
    double a_val = 0.0;
    #pragma unroll
    for (int j = 31; j >= 0; --j) {
        const double aj = __shfl(r, j) * __shfl(acc, j);
        if (i == j) a_val = aj;
        if (i < j)  acc -= aj * (double)row_sy[j];
    }

    const double g = (double)WSY[31 * 32 + 31] / (double)WYY[31 * 32 + 31];

    double u = -(double)VY[i];
    #pragma unroll
    for (int j = 0; j < 32; ++j)
        u -= __shfl(a_val, j) * (double)row_yy[j];
    u *= g;

    double tt = u;
    double b_val = 0.0;
    #pragma unroll
    for (int j = 0; j < 32; ++j) {
        const double bj = __shfl(r, j) * __shfl(tt, j);
        if (i == j) b_val = bj;
        const double dj = __shfl(a_val, j) - bj;
        if (i > j) tt += dj * (double)col_sy[j];
    }

    if (t < 32) {
        ws[off_cy + b * 32 + i] = (float)(g * a_val);
        ws[off_cs + b * 32 + i] = (float)(b_val - a_val);
    }
    if (t == 0) ws[off_g + b] = (float)g;
}

// ---------------------------------------------------------------------------
// Kernel C: out[b][d] = g*frc + sum_i cy[i]*y + cs[i]*s from the bf16
// [b][kst][k'][i] repack: each thread reads 2x64 B fully contiguous.
// grid = 64 b x 32 chunks (256 outputs each).
// ---------------------------------------------------------------------------
__global__ __launch_bounds__(256) void combine_bf16(
    const ush* __restrict__ sB, const ush* __restrict__ yB,
    const float* __restrict__ frc, const float* __restrict__ ws,
    float* __restrict__ out, long off_cy, long off_cs, long off_g)
{
    __shared__ float cy[32], cs[32];
    const int b  = blockIdx.x & 63;
    const int ch = blockIdx.x >> 6;
    const int t  = threadIdx.x;
    if (t < 32) { cy[t] = ws[off_cy + b * 32 + t]; cs[t] = ws[off_cs + b * 32 + t]; }
    __syncthreads();

    const int d   = (ch << 8) + t;
    const int kst = d >> 7, kp = d & 127;
    const size_t base = (((size_t)b * 64 + kst) * 128 + kp) * 32;

    uint4 ys[4], ss[4];
    #pragma unroll
    for (int q = 0; q < 4; ++q) {
        ys[q] = *(const uint4*)(yB + base + q * 8);
        ss[q] = *(const uint4*)(sB + base + q * 8);
    }

    float acc = ws[off_g + b] * frc[(size_t)b * Dh + d];
    #pragma unroll
    for (int q = 0; q < 4; ++q) {
        const uint_t uy[4] = {ys[q].x, ys[q].y, ys[q].z, ys[q].w};
        const uint_t us[4] = {ss[q].x, ss[q].y, ss[q].z, ss[q].w};
        #pragma unroll
        for (int m = 0; m < 4; ++m) {
            const int i0 = (q * 4 + m) * 2;
            acc += cy[i0]     * __uint_as_float(uy[m] << 16);
            acc += cy[i0 + 1] * __uint_as_float(uy[m] & 0xFFFF0000u);
            acc += cs[i0]     * __uint_as_float(us[m] << 16);
            acc += cs[i0 + 1] * __uint_as_float(us[m] & 0xFFFF0000u);
        }
    }
    out[(size_t)b * Dh + d] = acc;
}

// ---------------------------------------------------------------------------
// Fallback combine (f32 direct) if ws is too small for the bf16 repack.
// ---------------------------------------------------------------------------
__global__ __launch_bounds__(256) void combine_f32(
    const float* __restrict__ s, const float* __restrict__ y,
    const float* __restrict__ frc, const float* __restrict__ ws,
    float* __restrict__ out, long off_cy, long off_cs, long off_g)
{
    __shared__ float cy[32], cs[32];
    const int b  = blockIdx.x & 63;
    const int ch = blockIdx.x >> 6;
    const int t  = threadIdx.x;
    if (t < 32) { cy[t] = ws[off_cy + b * 32 + t]; cs[t] = ws[off_cs + b * 32 + t]; }
    __syncthreads();

    const int d = ch * 1024 + (t << 2);
    const size_t base = (size_t)b * Dh + d;
    const float g = ws[off_g + b];
    const float4 fv = *(const float4*)(frc + base);
    float4 acc;
    acc.x = g * fv.x; acc.y = g * fv.y; acc.z = g * fv.z; acc.w = g * fv.w;

    const float* py = y + base;
    const float* ps = s + base;
    #pragma unroll
    for (int grp = 0; grp < 4; ++grp) {
        float4 yv[8], sv[8];
        #pragma unroll
        for (int j = 0; j < 8; ++j) {
            const size_t off = (size_t)(grp * 8 + j) * ((size_t)Bh * Dh);
            yv[j] = *(const float4*)(py + off);
            sv[j] = *(const float4*)(ps + off);
        }
        #pragma unroll
        for (int j = 0; j < 8; ++j) {
            const float a1 = cy[grp * 8 + j], a2 = cs[grp * 8 + j];
            acc.x += a1 * yv[j].x + a2 * sv[j].x;
            acc.y += a1 * yv[j].y + a2 * sv[j].y;
            acc.z += a1 * yv[j].z + a2 * sv[j].z;
            acc.w += a1 * yv[j].w + a2 * sv[j].w;
        }
    }
    *(float4*)(out + base) = acc;
}

extern "C" void kernel_launch(void* const* d_in, const int* in_sizes, int n_in,
                              void* d_out, int out_size, void* d_ws, size_t ws_size,
                              hipStream_t stream)
{
    const float* s   = (const float*)d_in[0];
    const float* y   = (const float*)d_in[1];
    const float* frc = (const float*)d_in[2];
    float* out = (float*)d_out;
    float* ws  = (float*)d_ws;

    const long floats = (long)(ws_size / 4);

    const long P       = (long)NCHG * 64 * 1024;          // per-gram partial block
    const long off_psy = 0;
    const long off_pyy = P;
    const long off_pvs = 2 * P;
    const long off_pvy = off_pvs + (long)NCHG * 64 * 32;
    const long off_cy  = off_pvy + (long)NCHG * 64 * 32;
    const long off_cs  = off_cy + 2048;
    const long off_g   = off_cs + 2048;
    const long endc    = off_g + 64;

    const long off_sb  = (endc + 7) & ~7L;                // float offset, 16B-aligned
    const long elems   = (long)Mh * Bh * Dh;              // 16.78M bf16 per array
    const long off_yb  = off_sb + elems / 2;              // ush elems -> floats
    const int  do_bf16 = (off_yb + elems / 2) <= floats;

    ush* sB = (ush*)(ws + off_sb);
    ush* yB = (ush*)(ws + off_yb);

    gram_kernel<<<dim3(Bh * NCHG), dim3(256), 0, stream>>>(
        s, y, frc, ws, sB, yB, do_bf16, off_psy, off_pyy, off_pvs, off_pvy);
    recur_kernel<<<dim3(Bh), dim3(256), 0, stream>>>(
        ws, NCHG, off_psy, off_pyy, off_pvs, off_pvy, off_cy, off_cs, off_g);
    if (do_bf16) {
        combine_bf16<<<dim3(Bh * 32), dim3(256), 0, stream>>>(
            sB, yB, frc, ws, out, off_cy, off_cs, off_g);
    } else {
        combine_f32<<<dim3(Bh * 8), dim3(256), 0, stream>>>(
            s, y, frc, ws, out, off_cy, off_cs, off_g);
    }
}

// Round 5
// 1264.736 us; speedup vs baseline: 1.3707x; 1.3707x over previous
//
#include <hip/hip_runtime.h>

// Problem constants (reference: M, B, D = 32, 64, 8192)
#define Mh 32
#define Bh 64
#define Dh 8192
#define STG  128          // k per LDS stage in gram
#define NSTG 4            // stages per gram block (kch = 512)
#define NCHG 16           // k-chunks (gram grid = 64 b x 16)

typedef unsigned int   uint_t;
typedef unsigned short ush;

// async global->LDS DMA, 16 B per lane; LDS dest = uniform base + lane*16
__device__ __forceinline__ void async_cp16(const float* g, float* l) {
    __builtin_amdgcn_global_load_lds((const __attribute__((address_space(1))) uint_t*)g,
                                     (__attribute__((address_space(3))) uint_t*)l, 16, 0, 0);
}

__device__ __forceinline__ uint_t bf16rne(float x) {
    uint_t u = __float_as_uint(x);
    return (u + 0x7FFFu + ((u >> 16) & 1u)) >> 16;
}

// ---------------------------------------------------------------------------
// Kernel R: repack [i][b][k] -> [b][i][k] (f32 mode 2 / bf16 mode 1 / none 0)
// + frc dot products vs2[b*32+i] = s_i.frc, vy2 = y_i.frc.
// grid = 2048 blocks (b fastest), 256 threads. Contiguous 32-KB row runs
// both directions -> copy-class streaming.
// ---------------------------------------------------------------------------
__global__ __launch_bounds__(256) void repack_kernel(
    const float* __restrict__ s, const float* __restrict__ y,
    const float* __restrict__ frc,
    float* __restrict__ sT2, float* __restrict__ yT2,
    ush* __restrict__ sB, ush* __restrict__ yB, int mode,
    float* __restrict__ vs2, float* __restrict__ vy2)
{
    __shared__ float redA[256], redB[256];
    const int b = blockIdx.x & 63;
    const int i = blockIdx.x >> 6;
    const int t = threadIdx.x;
    const size_t src = ((size_t)i * Bh + b) * Dh;
    const size_t dst = ((size_t)b * Mh + i) * Dh;
    const size_t fb  = (size_t)b * Dh;

    float vs = 0.f, vy = 0.f;
    #pragma unroll
    for (int rep = 0; rep < 8; ++rep) {
        const int d = (rep << 10) + (t << 2);
        const float4 sv = *(const float4*)(s + src + d);
        const float4 yv = *(const float4*)(y + src + d);
        const float4 fv = *(const float4*)(frc + fb + d);
        vs += sv.x * fv.x + sv.y * fv.y + sv.z * fv.z + sv.w * fv.w;
        vy += yv.x * fv.x + yv.y * fv.y + yv.z * fv.z + yv.w * fv.w;
        if (mode == 2) {
            *(float4*)(sT2 + dst + d) = sv;
            *(float4*)(yT2 + dst + d) = yv;
        } else if (mode == 1) {
            const uint_t s0 = bf16rne(sv.x) | (bf16rne(sv.y) << 16);
            const uint_t s1 = bf16rne(sv.z) | (bf16rne(sv.w) << 16);
            const uint_t y0 = bf16rne(yv.x) | (bf16rne(yv.y) << 16);
            const uint_t y1 = bf16rne(yv.z) | (bf16rne(yv.w) << 16);
            *(uint2*)(sB + dst + d) = make_uint2(s0, s1);
            *(uint2*)(yB + dst + d) = make_uint2(y0, y1);
        }
    }
    redA[t] = vs; redB[t] = vy;
    __syncthreads();
    for (int off = 128; off >= 1; off >>= 1) {
        if (t < off) { redA[t] += redA[t + off]; redB[t] += redB[t + off]; }
        __syncthreads();
    }
    if (t == 0) { vs2[(b << 5) + i] = redA[0]; vy2[(b << 5) + i] = redB[0]; }
}

// ---------------------------------------------------------------------------
// Kernel A: batched Gram partials. grid = 64 b x 16 chunks, 256 threads,
// 32 KB LDS, lb(256,3) -> 3 blocks/CU. Reads via rpitch/bpitch so it works
// on either the transposed [b][i][k] copy (32-KB i-stride) or the original.
// Accumulators only (~80 live VGPRs by design) -> no spills expected.
// ---------------------------------------------------------------------------
__global__ __launch_bounds__(256, 3) void gram_kernel(
    const float* __restrict__ sa, const float* __restrict__ ya,
    float* __restrict__ ws, long rpitch, long bpitch,
    long off_psy, long off_pyy)
{
    __shared__ float sT[32 * STG];   // 16 KB
    __shared__ float yT[32 * STG];   // 16 KB

    const int b   = blockIdx.x & 63;
    const int ch  = blockIdx.x >> 6;
    const int chk = (ch + b) & 15;            // per-b chunk rotation
    const int t   = threadIdx.x;
    const int w   = t >> 6;
    const int l   = t & 63;
    const int tx  = l & 7;
    const int ty  = l >> 3;
    const int k0  = chk * (NSTG * STG);

    // staging geometry (validated R4): wave w issues instrs j=4w..4w+3;
    // instr j covers rows 2j (lanes 0-31), 2j+1 (lanes 32-63);
    // global f4-col = (l&31) ^ ((j>>1)&7)  [= (row>>2)&7].
    size_t rowoff[4];
    int    ldsoff[4];
    #pragma unroll
    for (int jj = 0; jj < 4; ++jj) {
        const int j   = (w << 2) + jj;
        const int row = (j << 1) + (l >> 5);
        const int cg  = (l & 31) ^ ((j >> 1) & 7);
        rowoff[jj] = (size_t)row * rpitch + (size_t)b * bpitch + (cg << 2);
        ldsoff[jj] = j << 8;
    }

    float acc_sy[4][4] = {};
    float acc_yy[4][4] = {};

    // prologue DMA: stage 0
    #pragma unroll
    for (int jj = 0; jj < 4; ++jj) {
        async_cp16(sa + rowoff[jj] + k0, &sT[ldsoff[jj]]);
        async_cp16(ya + rowoff[jj] + k0, &yT[ldsoff[jj]]);
    }

    for (int st = 0; st < NSTG; ++st) {
        __syncthreads();                      // drains DMA for stage st

        #pragma unroll
        for (int kk = 0; kk < 8; ++kk) {
            const int c0 = (w << 3) + kk;
            float4 xv[4];
            #pragma unroll
            for (int aa = 0; aa < 4; ++aa)
                xv[aa] = *(const float4*)&yT[((tx << 2) + aa) * STG + ((c0 ^ tx) << 2)];
            #pragma unroll
            for (int aa = 0; aa < 4; ++aa) {
                const float4 sv = *(const float4*)&sT[((ty << 2) + aa) * STG + ((c0 ^ ty) << 2)];
                const float4 tv = *(const float4*)&yT[((ty << 2) + aa) * STG + ((c0 ^ ty) << 2)];
                #pragma unroll
                for (int cc = 0; cc < 4; ++cc) {
                    acc_sy[aa][cc] += sv.x * xv[cc].x + sv.y * xv[cc].y
                                    + sv.z * xv[cc].z + sv.w * xv[cc].w;
                    acc_yy[aa][cc] += tv.x * xv[cc].x + tv.y * xv[cc].y
                                    + tv.z * xv[cc].z + tv.w * xv[cc].w;
                }
            }
        }

        __syncthreads();                      // all LDS reads of stage st done
        if (st + 1 < NSTG) {
            const int kg = k0 + (st + 1) * STG;
            #pragma unroll
            for (int jj = 0; jj < 4; ++jj) {
                async_cp16(sa + rowoff[jj] + kg, &sT[ldsoff[jj]]);
                async_cp16(ya + rowoff[jj] + kg, &yT[ldsoff[jj]]);
            }
        }
    }

    // cross-wave reduction (reuse sT: SY = sT[0:1024], YY = sT[1024:2048])
    __syncthreads();
    float* SY = &sT[0];
    float* YY = &sT[1024];
    for (int wv = 0; wv < 4; ++wv) {
        if (w == wv) {
            #pragma unroll
            for (int aa = 0; aa < 4; ++aa) {
                #pragma unroll
                for (int cc = 0; cc < 4; ++cc) {
                    const int e = ((ty << 2) + aa) * 32 + (tx << 2) + cc;
                    if (wv == 0) { SY[e] = acc_sy[aa][cc];  YY[e] = acc_yy[aa][cc]; }
                    else         { SY[e] += acc_sy[aa][cc]; YY[e] += acc_yy[aa][cc]; }
                }
            }
        }
        __syncthreads();
    }

    float* PSY = ws + off_psy + ((size_t)ch * Bh + b) * 1024;
    float* PYY = ws + off_pyy + ((size_t)ch * Bh + b) * 1024;
    *(float4*)&PSY[t << 2] = *(const float4*)&SY[t << 2];
    *(float4*)&PYY[t << 2] = *(const float4*)&YY[t << 2];
}

// ---------------------------------------------------------------------------
// Kernel B: sum 16 partials + M=32 f64 recursion. 1 block per b.
// vs/vy come directly from the repack kernel.
// ---------------------------------------------------------------------------
__global__ __launch_bounds__(256) void recur_kernel(
    float* __restrict__ ws,
    long off_psy, long off_pyy, long off_vs2, long off_vy2,
    long off_cy, long off_cs, long off_g)
{
    __shared__ float WSY[1024], WYY[1024], VS[32], VY[32];
    const int b = blockIdx.x;
    const int t = threadIdx.x;

    float4 a4 = make_float4(0.f, 0.f, 0.f, 0.f);
    float4 c4 = make_float4(0.f, 0.f, 0.f, 0.f);
    for (int ch = 0; ch < NCHG; ++ch) {
        const float4 u = *(const float4*)&ws[off_psy + ((size_t)ch * Bh + b) * 1024 + (t << 2)];
        const float4 v = *(const float4*)&ws[off_pyy + ((size_t)ch * Bh + b) * 1024 + (t << 2)];
        a4.x += u.x; a4.y += u.y; a4.z += u.z; a4.w += u.w;
        c4.x += v.x; c4.y += v.y; c4.z += v.z; c4.w += v.w;
    }
    *(float4*)&WSY[t << 2] = a4;
    *(float4*)&WYY[t << 2] = c4;
    if (t < 32) {
        VS[t] = ws[off_vs2 + (b << 5) + t];
        VY[t] = ws[off_vy2 + (b << 5) + t];
    }
    __syncthreads();
    if (t >= 64) return;

    const int i = t & 31;
    float row_sy[32], col_sy[32], row_yy[32];
    #pragma unroll
    for (int j = 0; j < 32; ++j) {
        row_sy[j] = WSY[i * 32 + j];
        col_sy[j] = WSY[j * 32 + i];
        row_yy[j] = WYY[i * 32 + j];
    }

    const double r = 1.0 / (double)row_sy[i];
    double acc = -(double)VS[i];
    double a_val = 0.0;
    #pragma unroll
    for (int j = 31; j >= 0; --j) {
        const double aj = __shfl(r, j) * __shfl(acc, j);
        if (i == j) a_val = aj;
        if (i < j)  acc -= aj * (double)row_sy[j];
    }

    const double g = (double)WSY[31 * 32 + 31] / (double)WYY[31 * 32 + 31];

    double u = -(double)VY[i];
    #pragma unroll
    for (int j = 0; j < 32; ++j)
        u -= __shfl(a_val, j) * (double)row_yy[j];
    u *= g;

    double tt = u;
    double b_val = 0.0;
    #pragma unroll
    for (int j = 0; j < 32; ++j) {
        const double bj = __shfl(r, j) * __shfl(tt, j);
        if (i == j) b_val = bj;
        const double dj = __shfl(a_val, j) - bj;
        if (i > j) tt += dj * (double)col_sy[j];
    }

    if (t < 32) {
        ws[off_cy + b * 32 + i] = (float)(g * a_val);
        ws[off_cs + b * 32 + i] = (float)(b_val - a_val);
    }
    if (t == 0) ws[off_g + b] = (float)g;
}

// ---------------------------------------------------------------------------
// Kernel C (mode 2): combine from f32 transposed copy [b][i][k].
// grid = 64 b x 8 chunks, 256 threads; i-stride 32 KB inside 256-KB window.
// ---------------------------------------------------------------------------
__global__ __launch_bounds__(256) void combine_f32T(
    const float* __restrict__ sT2, const float* __restrict__ yT2,
    const float* __restrict__ frc, const float* __restrict__ ws,
    float* __restrict__ out, long off_cy, long off_cs, long off_g)
{
    __shared__ float cy[32], cs[32];
    const int b  = blockIdx.x & 63;
    const int ch = blockIdx.x >> 6;
    const int t  = threadIdx.x;
    if (t < 32) { cy[t] = ws[off_cy + b * 32 + t]; cs[t] = ws[off_cs + b * 32 + t]; }
    __syncthreads();

    const int d = (ch << 10) + (t << 2);
    const size_t bb = (size_t)b * (Mh * Dh) + d;
    const float g = ws[off_g + b];
    const float4 fv = *(const float4*)(frc + (size_t)b * Dh + d);
    float4 acc;
    acc.x = g * fv.x; acc.y = g * fv.y; acc.z = g * fv.z; acc.w = g * fv.w;

    #pragma unroll
    for (int grp = 0; grp < 4; ++grp) {
        float4 yv[8], sv[8];
        #pragma unroll
        for (int j = 0; j < 8; ++j) {
            const size_t off = bb + (size_t)(grp * 8 + j) * Dh;
            yv[j] = *(const float4*)(yT2 + off);
            sv[j] = *(const float4*)(sT2 + off);
        }
        #pragma unroll
        for (int j = 0; j < 8; ++j) {
            const float a1 = cy[grp * 8 + j], a2 = cs[grp * 8 + j];
            acc.x += a1 * yv[j].x + a2 * sv[j].x;
            acc.y += a1 * yv[j].y + a2 * sv[j].y;
            acc.z += a1 * yv[j].z + a2 * sv[j].z;
            acc.w += a1 * yv[j].w + a2 * sv[j].w;
        }
    }
    *(float4*)(out + (size_t)b * Dh + d) = acc;
}

// ---------------------------------------------------------------------------
// Kernel C (mode 1): combine from bf16 transposed copy [b][i][k].
// grid = 64 b x 4 chunks, 256 threads, 8 k per thread.
// ---------------------------------------------------------------------------
__global__ __launch_bounds__(256) void combine_bf16T(
    const ush* __restrict__ sB, const ush* __restrict__ yB,
    const float* __restrict__ frc, const float* __restrict__ ws,
    float* __restrict__ out, long off_cy, long off_cs, long off_g)
{
    __shared__ float cy[32], cs[32];
    const int b  = blockIdx.x & 63;
    const int ch = blockIdx.x >> 6;
    const int t  = threadIdx.x;
    if (t < 32) { cy[t] = ws[off_cy + b * 32 + t]; cs[t] = ws[off_cs + b * 32 + t]; }
    __syncthreads();

    const int d = (ch << 11) + (t << 3);
    const size_t bb = (size_t)b * (Mh * Dh) + d;
    float acc[8] = {};

    #pragma unroll
    for (int grp = 0; grp < 4; ++grp) {
        uint4 yv[8], sv[8];
        #pragma unroll
        for (int j = 0; j < 8; ++j) {
            const size_t off = bb + (size_t)(grp * 8 + j) * Dh;
            yv[j] = *(const uint4*)(yB + off);
            sv[j] = *(const uint4*)(sB + off);
        }
        #pragma unroll
        for (int j = 0; j < 8; ++j) {
            const float a1 = cy[grp * 8 + j], a2 = cs[grp * 8 + j];
            const uint_t uy[4] = {yv[j].x, yv[j].y, yv[j].z, yv[j].w};
            const uint_t us[4] = {sv[j].x, sv[j].y, sv[j].z, sv[j].w};
            #pragma unroll
            for (int m = 0; m < 4; ++m) {
                acc[2*m]   += a1 * __uint_as_float(uy[m] << 16)
                            + a2 * __uint_as_float(us[m] << 16);
                acc[2*m+1] += a1 * __uint_as_float(uy[m] & 0xFFFF0000u)
                            + a2 * __uint_as_float(us[m] & 0xFFFF0000u);
            }
        }
    }
    const float g = ws[off_g + b];
    const size_t ob = (size_t)b * Dh + d;
    const float4 f0 = *(const float4*)(frc + ob);
    const float4 f1 = *(const float4*)(frc + ob + 4);
    float4 o0, o1;
    o0.x = acc[0] + g * f0.x; o0.y = acc[1] + g * f0.y;
    o0.z = acc[2] + g * f0.z; o0.w = acc[3] + g * f0.w;
    o1.x = acc[4] + g * f1.x; o1.y = acc[5] + g * f1.y;
    o1.z = acc[6] + g * f1.z; o1.w = acc[7] + g * f1.w;
    *(float4*)(out + ob)     = o0;
    *(float4*)(out + ob + 4) = o1;
}

// ---------------------------------------------------------------------------
// Kernel C (mode 0): direct from original layout (R2 fallback, proven).
// ---------------------------------------------------------------------------
__global__ __launch_bounds__(256) void combine_f32(
    const float* __restrict__ s, const float* __restrict__ y,
    const float* __restrict__ frc, const float* __restrict__ ws,
    float* __restrict__ out, long off_cy, long off_cs, long off_g)
{
    __shared__ float cy[32], cs[32];
    const int b  = blockIdx.x & 63;
    const int ch = blockIdx.x >> 6;
    const int t  = threadIdx.x;
    if (t < 32) { cy[t] = ws[off_cy + b * 32 + t]; cs[t] = ws[off_cs + b * 32 + t]; }
    __syncthreads();

    const int d = ch * 1024 + (t << 2);
    const size_t base = (size_t)b * Dh + d;
    const float g = ws[off_g + b];
    const float4 fv = *(const float4*)(frc + base);
    float4 acc;
    acc.x = g * fv.x; acc.y = g * fv.y; acc.z = g * fv.z; acc.w = g * fv.w;

    #pragma unroll
    for (int grp = 0; grp < 4; ++grp) {
        float4 yv[8], sv[8];
        #pragma unroll
        for (int j = 0; j < 8; ++j) {
            const size_t off = base + (size_t)(grp * 8 + j) * ((size_t)Bh * Dh);
            yv[j] = *(const float4*)(y + off);
            sv[j] = *(const float4*)(s + off);
        }
        #pragma unroll
        for (int j = 0; j < 8; ++j) {
            const float a1 = cy[grp * 8 + j], a2 = cs[grp * 8 + j];
            acc.x += a1 * yv[j].x + a2 * sv[j].x;
            acc.y += a1 * yv[j].y + a2 * sv[j].y;
            acc.z += a1 * yv[j].z + a2 * sv[j].z;
            acc.w += a1 * yv[j].w + a2 * sv[j].w;
        }
    }
    *(float4*)(out + base) = acc;
}

extern "C" void kernel_launch(void* const* d_in, const int* in_sizes, int n_in,
                              void* d_out, int out_size, void* d_ws, size_t ws_size,
                              hipStream_t stream)
{
    const float* s   = (const float*)d_in[0];
    const float* y   = (const float*)d_in[1];
    const float* frc = (const float*)d_in[2];
    float* out = (float*)d_out;
    float* ws  = (float*)d_ws;

    const long floats = (long)(ws_size / 4);

    const long off_psy = 0;                       // 16*64*1024 = 1,048,576
    const long off_pyy = 1048576;                 // + 1,048,576
    const long off_vs2 = 2097152;                 // + 2048
    const long off_vy2 = off_vs2 + 2048;
    const long off_cy  = off_vy2 + 2048;
    const long off_cs  = off_cy + 2048;
    const long off_g   = off_cs + 2048;
    const long endc    = off_g + 64;
    const long off_T   = (endc + 7) & ~7L;

    const long elems = (long)Mh * Bh * Dh;        // 16,777,216 per array
    const long need2 = off_T + 2 * elems;         // f32 transposed pair
    const long need1 = off_T + elems;             // bf16 transposed pair

    const int mode = (floats >= need2) ? 2 : (floats >= need1) ? 1 : 0;

    float* sT2 = ws + off_T;
    float* yT2 = ws + off_T + elems;
    ush*   sB  = (ush*)(ws + off_T);
    ush*   yB  = (ush*)(ws + off_T + elems / 2);

    // 1) repack + frc dots (always runs; mode 0 computes dots only)
    repack_kernel<<<dim3(Bh * Mh), dim3(256), 0, stream>>>(
        s, y, frc, sT2, yT2, sB, yB, mode, ws + off_vs2, ws + off_vy2);

    // 2) gram partials — transposed layout if available, else original
    if (mode == 2) {
        gram_kernel<<<dim3(Bh * NCHG), dim3(256), 0, stream>>>(
            sT2, yT2, ws, (long)Dh, (long)(Mh * Dh), off_psy, off_pyy);
    } else {
        gram_kernel<<<dim3(Bh * NCHG), dim3(256), 0, stream>>>(
            s, y, ws, (long)(Bh * Dh), (long)Dh, off_psy, off_pyy);
    }

    // 3) recursion
    recur_kernel<<<dim3(Bh), dim3(256), 0, stream>>>(
        ws, off_psy, off_pyy, off_vs2, off_vy2, off_cy, off_cs, off_g);

    // 4) combine
    if (mode == 2) {
        combine_f32T<<<dim3(Bh * 8), dim3(256), 0, stream>>>(
            sT2, yT2, frc, ws, out, off_cy, off_cs, off_g);
    } else if (mode == 1) {
        combine_bf16T<<<dim3(Bh * 4), dim3(256), 0, stream>>>(
            sB, yB, frc, ws, out, off_cy, off_cs, off_g);
    } else {
        combine_f32<<<dim3(Bh * 8), dim3(256), 0, stream>>>(
            s, y, frc, ws, out, off_cy, off_cs, off_g);
    }
}

// Round 6
// 234.339 us; speedup vs baseline: 7.3979x; 5.3970x over previous
//
#include <hip/hip_runtime.h>

// Problem constants (reference: M, B, D = 32, 64, 8192)
#define Mh 32
#define Bh 64
#define Dh 8192
#define NCHG 16           // k-chunks for gram (grid = 64 b x 16)
#define KCH 512           // k per chunk
#define STG 64            // k per LDS stage
#define NST (KCH / STG)   // 8 stages

// Workspace layout (float offsets). Total ~12.3 MB — small, single path.
#define OFF_PSY 0L                        // [16][64][1024] partial Wsy
#define OFF_PYY 1048576L                  // [16][64][1024] partial Wyy
#define OFF_PVS 2097152L                  // [16][64][32]   partial s_i.frc
#define OFF_PVY 2129920L                  // [16][64][32]   partial y_i.frc
#define OFF_CY  2162688L                  // [64][32] g*a_i
#define OFF_CS  2164736L                  // [64][32] b_i-a_i
#define OFF_G   2166784L                  // [64]
#define OFF_PC  2166848L                  // [2][64][8192] combine partials

// ---------------------------------------------------------------------------
// Kernel A: batched Gram partials. grid = 64 b x 16 chunks, 256 threads.
// R1-proven structure: plain float4 global loads -> LDS stores (loads issued
// before the barrier to overlap prior compute), XOR swizzle col^(row>>2),
// accumulate 4x4 register tiles, cross-wave LDS reduction, plain writes.
// NO launch-bounds min-arg, NO global_load_lds, NO cross-stage reg prefetch.
// ---------------------------------------------------------------------------
__global__ __launch_bounds__(256) void gram_kernel(
    const float* __restrict__ s, const float* __restrict__ y,
    const float* __restrict__ frc, float* __restrict__ ws)
{
    __shared__ float sT[32 * STG];   // 8 KB
    __shared__ float yT[32 * STG];   // 8 KB
    __shared__ float fT[STG];        // 256 B

    const int b   = blockIdx.x & 63;
    const int ch  = blockIdx.x >> 6;          // partial index 0..15
    const int chk = (ch + b) & 15;            // per-b chunk rotation
    const int k0  = chk * KCH;
    const int t   = threadIdx.x;
    const int w   = t >> 6;
    const int l   = t & 63;
    const int tx  = l & 7;
    const int ty  = l >> 3;

    // staging map: rep r covers row = (t+256r)>>4, LDS f4-col cl = t&15;
    // LDS[row][cl] holds logical col (cl ^ (row>>2)) -> compute reads
    // logical c0 at LDS col (c0 ^ (row>>2)). 16 f4/row = 256 B contiguous.
    size_t go[2]; int la[2];
    #pragma unroll
    for (int r = 0; r < 2; ++r) {
        const int row = (t + (r << 8)) >> 4;
        const int cl  = t & 15;
        const int gc  = cl ^ (row >> 2);
        go[r] = ((size_t)row * Bh + b) * Dh + (gc << 2);
        la[r] = (row << 6) + (cl << 2);
    }
    const size_t fb = (size_t)b * Dh;

    float asy[4][4] = {};
    float ayy[4][4] = {};
    float avs[4] = {}, avy[4] = {};

    for (int st = 0; st < NST; ++st) {
        const int k = k0 + st * STG;
        // global loads issued before the barrier (overlap prior compute)
        const float4 s0 = *(const float4*)(s + go[0] + k);
        const float4 y0 = *(const float4*)(y + go[0] + k);
        const float4 s1 = *(const float4*)(s + go[1] + k);
        const float4 y1 = *(const float4*)(y + go[1] + k);
        float4 fv4 = make_float4(0.f, 0.f, 0.f, 0.f);
        if (t < 16) fv4 = *(const float4*)(frc + fb + k + (t << 2));

        __syncthreads();                      // prior stage's compute done
        *(float4*)&sT[la[0]] = s0;
        *(float4*)&yT[la[0]] = y0;
        *(float4*)&sT[la[1]] = s1;
        *(float4*)&yT[la[1]] = y1;
        if (t < 16) *(float4*)&fT[t << 2] = fv4;
        __syncthreads();

        // wave w covers logical f4-cols [4w, 4w+4)
        #pragma unroll
        for (int kk = 0; kk < 4; ++kk) {
            const int c0 = (w << 2) + kk;
            float4 xv[4];
            #pragma unroll
            for (int aa = 0; aa < 4; ++aa)
                xv[aa] = *(const float4*)&yT[(((tx << 2) + aa) << 6) + ((c0 ^ tx) << 2)];
            const float4 fv = *(const float4*)&fT[c0 << 2];
            #pragma unroll
            for (int aa = 0; aa < 4; ++aa) {
                const float4 sv = *(const float4*)&sT[(((ty << 2) + aa) << 6) + ((c0 ^ ty) << 2)];
                const float4 tv = *(const float4*)&yT[(((ty << 2) + aa) << 6) + ((c0 ^ ty) << 2)];
                #pragma unroll
                for (int cc = 0; cc < 4; ++cc) {
                    asy[aa][cc] += sv.x * xv[cc].x + sv.y * xv[cc].y
                                 + sv.z * xv[cc].z + sv.w * xv[cc].w;
                    ayy[aa][cc] += tv.x * xv[cc].x + tv.y * xv[cc].y
                                 + tv.z * xv[cc].z + tv.w * xv[cc].w;
                }
                avs[aa] += sv.x * fv.x + sv.y * fv.y + sv.z * fv.z + sv.w * fv.w;
                avy[aa] += tv.x * fv.x + tv.y * fv.y + tv.z * fv.z + tv.w * fv.w;
            }
        }
    }

    // cross-wave reduction: SY = sT[0:1024], YY = sT[1024:2048], VV = fT
    __syncthreads();
    float* SY = &sT[0];
    float* YY = &sT[1024];
    float* VV = &fT[0];
    for (int wv = 0; wv < 4; ++wv) {
        if (w == wv) {
            #pragma unroll
            for (int aa = 0; aa < 4; ++aa) {
                #pragma unroll
                for (int cc = 0; cc < 4; ++cc) {
                    const int e = ((ty << 2) + aa) * 32 + (tx << 2) + cc;
                    if (wv == 0) { SY[e] = asy[aa][cc];  YY[e] = ayy[aa][cc]; }
                    else         { SY[e] += asy[aa][cc]; YY[e] += ayy[aa][cc]; }
                }
                if (tx == 0) {
                    const int i = (ty << 2) + aa;
                    if (wv == 0) { VV[i] = avs[aa];  VV[32 + i] = avy[aa]; }
                    else         { VV[i] += avs[aa]; VV[32 + i] += avy[aa]; }
                }
            }
        }
        __syncthreads();
    }

    float* PSY = ws + OFF_PSY + ((size_t)ch * Bh + b) * 1024;
    float* PYY = ws + OFF_PYY + ((size_t)ch * Bh + b) * 1024;
    *(float4*)&PSY[t << 2] = *(const float4*)&SY[t << 2];
    *(float4*)&PYY[t << 2] = *(const float4*)&YY[t << 2];
    if (t < 32)      ws[OFF_PVS + (ch * 64 + b) * 32 + t] = VV[t];
    else if (t < 64) ws[OFF_PVY + (ch * 64 + b) * 32 + (t - 32)] = VV[t];
}

// ---------------------------------------------------------------------------
// Kernel B: reduce 16 partials, then the M=32 f64 recursion. 1 block per b.
// ---------------------------------------------------------------------------
__global__ __launch_bounds__(256) void recur_kernel(float* __restrict__ ws)
{
    __shared__ float WSY[1024], WYY[1024], VS[32], VY[32];
    const int b = blockIdx.x;
    const int t = threadIdx.x;

    float4 a4 = make_float4(0.f, 0.f, 0.f, 0.f);
    float4 c4 = make_float4(0.f, 0.f, 0.f, 0.f);
    for (int ch = 0; ch < NCHG; ++ch) {
        const float4 u = *(const float4*)&ws[OFF_PSY + ((size_t)ch * Bh + b) * 1024 + (t << 2)];
        const float4 v = *(const float4*)&ws[OFF_PYY + ((size_t)ch * Bh + b) * 1024 + (t << 2)];
        a4.x += u.x; a4.y += u.y; a4.z += u.z; a4.w += u.w;
        c4.x += v.x; c4.y += v.y; c4.z += v.z; c4.w += v.w;
    }
    *(float4*)&WSY[t << 2] = a4;
    *(float4*)&WYY[t << 2] = c4;
    if (t < 32) {
        float av = 0.f, cv = 0.f;
        for (int ch = 0; ch < NCHG; ++ch) {
            av += ws[OFF_PVS + (ch * 64 + b) * 32 + t];
            cv += ws[OFF_PVY + (ch * 64 + b) * 32 + t];
        }
        VS[t] = av; VY[t] = cv;
    }
    __syncthreads();
    if (t >= 64) return;

    const int i = t & 31;
    float row_sy[32], col_sy[32], row_yy[32];
    #pragma unroll
    for (int j = 0; j < 32; ++j) {
        row_sy[j] = WSY[i * 32 + j];
        col_sy[j] = WSY[j * 32 + i];
        row_yy[j] = WYY[i * 32 + j];
    }

    const double r = 1.0 / (double)row_sy[i];
    double acc = -(double)VS[i];
    double a_val = 0.0;
    #pragma unroll
    for (int j = 31; j >= 0; --j) {
        const double aj = __shfl(r, j) * __shfl(acc, j);
        if (i == j) a_val = aj;
        if (i < j)  acc -= aj * (double)row_sy[j];
    }

    const double g = (double)WSY[31 * 32 + 31] / (double)WYY[31 * 32 + 31];

    double u = -(double)VY[i];
    #pragma unroll
    for (int j = 0; j < 32; ++j)
        u -= __shfl(a_val, j) * (double)row_yy[j];
    u *= g;

    double tt = u;
    double b_val = 0.0;
    #pragma unroll
    for (int j = 0; j < 32; ++j) {
        const double bj = __shfl(r, j) * __shfl(tt, j);
        if (i == j) b_val = bj;
        const double dj = __shfl(a_val, j) - bj;
        if (i > j) tt += dj * (double)col_sy[j];
    }

    if (t < 32) {
        ws[OFF_CY + b * 32 + i] = (float)(g * a_val);
        ws[OFF_CS + b * 32 + i] = (float)(b_val - a_val);
    }
    if (t == 0) ws[OFF_G + b] = (float)g;
}

// ---------------------------------------------------------------------------
// Kernel C1: half-combine. grid = 64 b x 8 chunks x 2 halves = 1024 blocks.
// Half h sums i in [16h,16h+16); partial f4 written to ws. 2x waves vs R2.
// ---------------------------------------------------------------------------
__global__ __launch_bounds__(256) void combine_part(
    const float* __restrict__ s, const float* __restrict__ y,
    const float* __restrict__ ws, float* __restrict__ pc)
{
    __shared__ float cy[16], cs[16];
    const int b  = blockIdx.x & 63;
    const int ch = (blockIdx.x >> 6) & 7;
    const int h  = blockIdx.x >> 9;
    const int t  = threadIdx.x;
    if (t < 16) {
        cy[t] = ws[OFF_CY + (b << 5) + (h << 4) + t];
        cs[t] = ws[OFF_CS + (b << 5) + (h << 4) + t];
    }
    __syncthreads();

    const int d = (ch << 10) + (t << 2);
    const size_t base = (size_t)b * Dh + d;
    float4 acc = make_float4(0.f, 0.f, 0.f, 0.f);

    #pragma unroll
    for (int grp = 0; grp < 2; ++grp) {
        float4 yv[8], sv[8];
        #pragma unroll
        for (int j = 0; j < 8; ++j) {
            const int i = (h << 4) + (grp << 3) + j;
            const size_t off = base + (size_t)i * ((size_t)Bh * Dh);
            yv[j] = *(const float4*)(y + off);
            sv[j] = *(const float4*)(s + off);
        }
        #pragma unroll
        for (int j = 0; j < 8; ++j) {
            const float a1 = cy[(grp << 3) + j], a2 = cs[(grp << 3) + j];
            acc.x += a1 * yv[j].x + a2 * sv[j].x;
            acc.y += a1 * yv[j].y + a2 * sv[j].y;
            acc.z += a1 * yv[j].z + a2 * sv[j].z;
            acc.w += a1 * yv[j].w + a2 * sv[j].w;
        }
    }
    *(float4*)(pc + ((size_t)h * Bh * Dh) + base) = acc;
}

// ---------------------------------------------------------------------------
// Kernel C2: out = g*frc + pc[0] + pc[1]. grid = 512, trivial streaming.
// ---------------------------------------------------------------------------
__global__ __launch_bounds__(256) void combine_fin(
    const float* __restrict__ frc, const float* __restrict__ ws,
    const float* __restrict__ pc, float* __restrict__ out)
{
    const int b  = blockIdx.x & 63;
    const int ch = blockIdx.x >> 6;
    const int t  = threadIdx.x;
    const int d  = (ch << 10) + (t << 2);
    const size_t base = (size_t)b * Dh + d;
    const float g = ws[OFF_G + b];
    const float4 fv = *(const float4*)(frc + base);
    const float4 p0 = *(const float4*)(pc + base);
    const float4 p1 = *(const float4*)(pc + (size_t)Bh * Dh + base);
    float4 o;
    o.x = g * fv.x + p0.x + p1.x;
    o.y = g * fv.y + p0.y + p1.y;
    o.z = g * fv.z + p0.z + p1.z;
    o.w = g * fv.w + p0.w + p1.w;
    *(float4*)(out + base) = o;
}

extern "C" void kernel_launch(void* const* d_in, const int* in_sizes, int n_in,
                              void* d_out, int out_size, void* d_ws, size_t ws_size,
                              hipStream_t stream)
{
    const float* s   = (const float*)d_in[0];
    const float* y   = (const float*)d_in[1];
    const float* frc = (const float*)d_in[2];
    float* out = (float*)d_out;
    float* ws  = (float*)d_ws;
    float* pc  = ws + OFF_PC;

    gram_kernel<<<dim3(Bh * NCHG), dim3(256), 0, stream>>>(s, y, frc, ws);
    recur_kernel<<<dim3(Bh), dim3(256), 0, stream>>>(ws);
    combine_part<<<dim3(Bh * 8 * 2), dim3(256), 0, stream>>>(s, y, ws, pc);
    combine_fin<<<dim3(Bh * 8), dim3(256), 0, stream>>>(frc, ws, pc, out);
}